// Round 9
// baseline (272.646 us; speedup 1.0000x reference)
//
#include <hip/hip_runtime.h>
#include <hip/hip_bf16.h>

#define PTOT   32768
#define KNB    16
#define NCLOUD 16
#define OUTC   512
#define A1S    168   // sa2 A1 row stride in ushort (336 B, 16B-aligned)
#define A2S    264   // sa2 A2 row stride in ushort (528 B, 16B-aligned)

typedef __attribute__((ext_vector_type(8)))  short v8bf;
typedef __attribute__((ext_vector_type(16))) float v16f;

__device__ __forceinline__ unsigned short f2b(float v) {
    __hip_bfloat16 h = __float2bfloat16(v);
    return *reinterpret_cast<unsigned short*>(&h);
}
__device__ __forceinline__ float b2f(unsigned short u) {
    return __uint_as_float(((unsigned)u) << 16);
}
__device__ __forceinline__ unsigned pk2(float a, float b) {
    return (unsigned)f2b(a) | ((unsigned)f2b(b) << 16);
}
__device__ __forceinline__ unsigned fenc(float f) {
    unsigned u = __float_as_uint(f);
    return (u & 0x80000000u) ? ~u : (u | 0x80000000u);
}
__device__ __forceinline__ float fdec(unsigned u) {
    unsigned b = (u & 0x80000000u) ? (u & 0x7FFFFFFFu) : ~u;
    return __uint_as_float(b);
}
__device__ __forceinline__ v16f zero16() {
    v16f z;
    #pragma unroll
    for (int i = 0; i < 16; ++i) z[i] = 0.0f;
    return z;
}

// ======= sa1 (MFMA): 16 points/block, single-pass M=256 (R6, unchanged) ====
__global__ __launch_bounds__(256) void sa1_kernel(
    const float* __restrict__ pos, const int* __restrict__ nbr,
    const float* __restrict__ W1, const float* __restrict__ b1,
    const float* __restrict__ W2, const float* __restrict__ b2,
    const float* __restrict__ W3, const float* __restrict__ W4,
    unsigned short* __restrict__ W3s, unsigned short* __restrict__ W4s,
    unsigned* __restrict__ encbuf,
    unsigned short* __restrict__ x1b)
{
    __shared__ unsigned short A1d[256 * 16];   // 8 KB (also prep scratch)
    __shared__ unsigned short A2[256 * 72];    // 36 KB
    const int tid  = threadIdx.x;
    const int lane = tid & 63;
    const int wave = tid >> 6;
    const int l31  = lane & 31;
    const int h    = lane >> 5;

    // ---- absorbed prep, coalesced via LDS transpose (blocks 0..49)
    {
        const int b = blockIdx.x;
        if (b < 32) {                          // W4s tile c2 = b: 8 rows x 512 cols
            #pragma unroll
            for (int it = 0; it < 16; ++it) {
                int e = tid + it * 256;        // 0..4095
                int jj = e >> 9, n = e & 511;
                A1d[e] = f2b(W4[(b * 8 + jj) * 512 + n]);   // coalesced read
            }
            __syncthreads();
            #pragma unroll
            for (int it = 0; it < 16; ++it) {
                int o = tid + it * 256;        // W4s idx = b*4096 + n*8 + j
                W4s[b * 4096 + o] = A1d[(o & 7) * 512 + (o >> 3)];  // coalesced write
            }
            __syncthreads();                   // A1d reusable below
        } else if (b < 50) {                   // W3s tile c2 = b-32: 8 rows x 256 cols
            int c2 = b - 32;
            #pragma unroll
            for (int it = 0; it < 8; ++it) {
                int e = tid + it * 256;        // 0..2047
                int jj = e >> 8, n = e & 255;
                int k = c2 * 8 + jj;
                A1d[e] = f2b(k < 131 ? W3[k * 256 + n] : 0.0f);
            }
            __syncthreads();
            #pragma unroll
            for (int it = 0; it < 8; ++it) {
                int o = tid + it * 256;        // W3s idx = c2*2048 + n*8 + j
                W3s[c2 * 2048 + o] = A1d[(o & 7) * 256 + (o >> 3)];
            }
            __syncthreads();
        }
        if (b == 2047) {                       // encbuf init (fenc-domain -inf)
            for (int i = tid; i < NCLOUD * OUTC; i += 256) encbuf[i] = 0u;
        }
    }

    // ---- weight fragments from global fp32 (block-invariant)
    const int c1 = (wave >> 1) * 32 + l31;       // G1 col (col-tile = wave>>1)
    v8bf b1f;
    #pragma unroll
    for (int i = 0; i < 8; ++i) b1f[i] = 0;
    if (h == 0) {   // k=0..2 real, rest zero
        b1f[0] = (short)f2b(W1[c1]);
        b1f[1] = (short)f2b(W1[64 + c1]);
        b1f[2] = (short)f2b(W1[128 + c1]);
    }
    const float b1v = b1[c1];
    const int cW2 = wave * 32 + l31;             // G2 col (col-tile = wave)
    v8bf B2[4];
    #pragma unroll
    for (int kc = 0; kc < 4; ++kc)
        #pragma unroll
        for (int j = 0; j < 8; ++j)
            B2[kc][j] = (short)f2b(W2[(kc * 16 + h * 8 + j) * 128 + cW2]);
    const float b2v = b2[cW2];

    const int p0 = blockIdx.x * 16;

    // ---- stage A1d: 256 rows = (point, nbr), one thread per row
    {
        int r = tid;
        int j = nbr[p0 * KNB + r];
        int p = p0 + (r >> 4);
        v8bf z;
        #pragma unroll
        for (int i = 0; i < 8; ++i) z[i] = 0;
        v8bf dv = z;
        dv[0] = (short)f2b(pos[j * 3 + 0] - pos[p * 3 + 0]);
        dv[1] = (short)f2b(pos[j * 3 + 1] - pos[p * 3 + 1]);
        dv[2] = (short)f2b(pos[j * 3 + 2] - pos[p * 3 + 2]);
        *(v8bf*)(A1d + r * 16)     = dv;
        *(v8bf*)(A1d + r * 16 + 8) = z;
    }
    __syncthreads();

    // ---- G1: wave covers col-tile (wave>>1), row-tiles {(wave&1)+2*rr}
    #pragma unroll
    for (int rr = 0; rr < 4; ++rr) {
        const int rt = (wave & 1) + rr * 2;
        v8bf a = *(const v8bf*)(A1d + (rt * 32 + l31) * 16 + h * 8);
        v16f acc = __builtin_amdgcn_mfma_f32_32x32x16_bf16(a, b1f, zero16(), 0, 0, 0);
        #pragma unroll
        for (int r = 0; r < 16; ++r) {
            int row = rt * 32 + (r & 3) + 8 * (r >> 2) + 4 * h;
            A2[row * 72 + c1] = f2b(fmaxf(acc[r] + b1v, 0.0f));
        }
    }
    __syncthreads();

    // ---- G2: wave's col-tile over 8 row-tiles; per-rt max -> 2 points each
    #pragma unroll
    for (int rt = 0; rt < 8; ++rt) {
        v16f acc = zero16();
        #pragma unroll
        for (int kc = 0; kc < 4; ++kc) {
            v8bf a = *(const v8bf*)(A2 + (rt * 32 + l31) * 72 + kc * 16 + h * 8);
            acc = __builtin_amdgcn_mfma_f32_32x32x16_bf16(a, B2[kc], acc, 0, 0, 0);
        }
        float ma = acc[0], mb = acc[8];
        #pragma unroll
        for (int r = 1; r < 8; ++r) { ma = fmaxf(ma, acc[r]); mb = fmaxf(mb, acc[8 + r]); }
        ma = fmaxf(ma, __shfl_xor(ma, 32));
        mb = fmaxf(mb, __shfl_xor(mb, 32));
        int p = p0 + rt * 2 + h;
        float m = h ? mb : ma;
        x1b[p * 128 + cW2] = f2b(m + b2v);
    }
}

// ======= ymap (new): y[p][n] = x1[p] @ W3[:128] + b3  (per-POINT, once) =====
// The j-dependent part of sa2's GEMM1, deduplicated across the ~16 neighbor
// occurrences of each point. 128 points/block, 256 blocks, ILP-4 MFMA.
__global__ __launch_bounds__(256) void ymap_kernel(
    const unsigned short* __restrict__ x1b,
    const unsigned short* __restrict__ W3s,
    const float* __restrict__ b3,
    unsigned short* __restrict__ y)
{
    __shared__ unsigned short X[128 * 128];    // 32 KB
    const int tid  = threadIdx.x;
    const int lane = tid & 63;
    const int wave = tid >> 6;
    const int l31  = lane & 31;
    const int h    = lane >> 5;
    const int p0   = blockIdx.x * 128;

    // stage x1 rows (contiguous, coalesced): 2 threads/row, 128 B each
    {
        int r = tid >> 1, q = tid & 1;
        const uint4* src = (const uint4*)(x1b + (p0 + r) * 128 + q * 64);
        uint4* dst = (uint4*)(X + r * 128 + q * 64);
        #pragma unroll
        for (int i = 0; i < 8; ++i) dst[i] = src[i];
    }
    __syncthreads();

    #pragma unroll
    for (int ci = 0; ci < 2; ++ci) {
        const int ct = wave * 2 + ci;          // col-tile 0..7
        const int n  = ct * 32 + l31;
        v8bf Bf[8];
        #pragma unroll
        for (int kc = 0; kc < 8; ++kc)
            Bf[kc] = *(const v8bf*)(W3s + (((kc * 2 + h) * 256 + n) << 3));
        const float b3v = b3[n];
        v16f a0 = zero16(), a1 = zero16(), a2 = zero16(), a3 = zero16();
        #pragma unroll
        for (int kc = 0; kc < 8; ++kc) {
            v8bf x0 = *(const v8bf*)(X + (0 * 32 + l31) * 128 + kc * 16 + h * 8);
            v8bf x1 = *(const v8bf*)(X + (1 * 32 + l31) * 128 + kc * 16 + h * 8);
            v8bf x2 = *(const v8bf*)(X + (2 * 32 + l31) * 128 + kc * 16 + h * 8);
            v8bf x3 = *(const v8bf*)(X + (3 * 32 + l31) * 128 + kc * 16 + h * 8);
            a0 = __builtin_amdgcn_mfma_f32_32x32x16_bf16(x0, Bf[kc], a0, 0, 0, 0);
            a1 = __builtin_amdgcn_mfma_f32_32x32x16_bf16(x1, Bf[kc], a1, 0, 0, 0);
            a2 = __builtin_amdgcn_mfma_f32_32x32x16_bf16(x2, Bf[kc], a2, 0, 0, 0);
            a3 = __builtin_amdgcn_mfma_f32_32x32x16_bf16(x3, Bf[kc], a3, 0, 0, 0);
        }
        // D layout: col = n, row = rt*32 + (r&3)+8*(r>>2)+4h  (proven pattern)
        #pragma unroll
        for (int r = 0; r < 16; ++r) {
            int cr = (r & 3) + 8 * (r >> 2) + 4 * h;
            y[(p0 + 0  + cr) * 256 + n] = f2b(a0[r] + b3v);
            y[(p0 + 32 + cr) * 256 + n] = f2b(a1[r] + b3v);
            y[(p0 + 64 + cr) * 256 + n] = f2b(a2[r] + b3v);
            y[(p0 + 96 + cr) * 256 + n] = f2b(a3[r] + b3v);
        }
    }
}

// ==== sa2y (new): gather-y + rank-3 VALU update -> A2, then proven GEMM2 ====
// Replaces sa2's per-pair GEMM1 (72 MFMAs/block + A1 stage + scalar-transpose
// + 2 barriers) with: A2[r][n] = relu(y[j_r][n] + d_r . W3[128:131][n]).
// Per thread: row r = tid&127, channel half qq = wave>>1 (wave-uniform ->
// W3d loads scalar); 16 chunks of 8 ch: v8bf y-gather + 24 fma + b128 LDS
// write. One barrier total. GEMM2 = R6-exact body.
__global__ __launch_bounds__(256) void sa2y_kernel(
    const float* __restrict__ pos, const int* __restrict__ nbr,
    const int* __restrict__ batch,
    const float* __restrict__ W3,
    const unsigned short* __restrict__ W4s, const float* __restrict__ b4,
    const unsigned short* __restrict__ y, unsigned* __restrict__ encbuf)
{
    __shared__ unsigned short S[128 * A2S];   // 67584 B (A2 only)
    const int tid  = threadIdx.x;
    const int lane = tid & 63;
    const int wave = tid >> 6;
    const int l31  = lane & 31;
    const int h    = lane >> 5;
    const int p0   = blockIdx.x * 8;

    // ---- phase A: build A2 directly
    {
        const int r  = tid & 127;
        const int qq = __builtin_amdgcn_readfirstlane(wave >> 1);  // wave-uniform
        const int j  = nbr[p0 * KNB + r];
        const int p  = p0 + (r >> 4);
        const float d0 = pos[j * 3 + 0] - pos[p * 3 + 0];
        const float d1 = pos[j * 3 + 1] - pos[p * 3 + 1];
        const float d2 = pos[j * 3 + 2] - pos[p * 3 + 2];
        const float* W3d = W3 + 128 * 256;     // rows 128..130, fp32
        #pragma unroll
        for (int c = 0; c < 16; ++c) {
            const int n0 = qq * 128 + c * 8;
            v8bf yv = *(const v8bf*)(y + j * 256 + n0);
            float se[8];
            #pragma unroll
            for (int e = 0; e < 8; ++e) {
                float s = b2f((unsigned short)yv[e])
                        + d0 * W3d[n0 + e]
                        + d1 * W3d[256 + n0 + e]
                        + d2 * W3d[512 + n0 + e];
                se[e] = fmaxf(s, 0.0f);
            }
            uint4 u;
            u.x = pk2(se[0], se[1]); u.y = pk2(se[2], se[3]);
            u.z = pk2(se[4], se[5]); u.w = pk2(se[6], se[7]);
            *reinterpret_cast<uint4*>(S + r * A2S + n0) = u;
        }
    }
    __syncthreads();   // A2 ready — the only barrier

    // ---- GEMM2: ct-pair outer (B held, reused by both row-tile-pairs)
    const int cloud = batch[p0];
    #pragma unroll
    for (int cp = 0; cp < 2; ++cp) {
        const int ct0 = wave * 4 + cp * 2;
        const int n0 = ct0 * 32 + l31;
        const int n1 = (ct0 + 1) * 32 + l31;
        v8bf B2a[16], B2b[16];
        #pragma unroll
        for (int kc = 0; kc < 16; ++kc) {
            int c2 = kc * 2 + h;
            B2a[kc] = *(const v8bf*)(W4s + ((c2 * 512 + n0) << 3));
            B2b[kc] = *(const v8bf*)(W4s + ((c2 * 512 + n1) << 3));
        }
        float rm0 = -3.4e38f, rm1 = -3.4e38f;
        #pragma unroll
        for (int rtp = 0; rtp < 2; ++rtp) {
            v16f a00 = zero16(), a01 = zero16(), a10 = zero16(), a11 = zero16();
            #pragma unroll
            for (int kc = 0; kc < 16; ++kc) {
                v8bf a0 = *(const v8bf*)(S + (rtp * 64 + l31)      * A2S + kc * 16 + h * 8);
                v8bf a1 = *(const v8bf*)(S + (rtp * 64 + 32 + l31) * A2S + kc * 16 + h * 8);
                a00 = __builtin_amdgcn_mfma_f32_32x32x16_bf16(a0, B2a[kc], a00, 0, 0, 0);
                a10 = __builtin_amdgcn_mfma_f32_32x32x16_bf16(a1, B2a[kc], a10, 0, 0, 0);
                a01 = __builtin_amdgcn_mfma_f32_32x32x16_bf16(a0, B2b[kc], a01, 0, 0, 0);
                a11 = __builtin_amdgcn_mfma_f32_32x32x16_bf16(a1, B2b[kc], a11, 0, 0, 0);
            }
            #pragma unroll
            for (int r = 0; r < 16; ++r) {
                rm0 = fmaxf(rm0, fmaxf(a00[r], a10[r]));
                rm1 = fmaxf(rm1, fmaxf(a01[r], a11[r]));
            }
        }
        rm0 = fmaxf(rm0, __shfl_xor(rm0, 32));
        rm1 = fmaxf(rm1, __shfl_xor(rm1, 32));
        rm0 += b4[ct0 * 32 + l31];
        rm1 += b4[(ct0 + 1) * 32 + l31];
        if (lane < 32) {
            atomicMax(&encbuf[cloud * OUTC + ct0 * 32 + l31], fenc(rm0));
            atomicMax(&encbuf[cloud * OUTC + (ct0 + 1) * 32 + l31], fenc(rm1));
        }
    }
}

// ==== sa2 (fallback, R6-exact): used when workspace can't hold y ===========
__global__ __launch_bounds__(256) void sa2_kernel(
    const float* __restrict__ pos, const int* __restrict__ nbr,
    const int* __restrict__ batch,
    const unsigned short* __restrict__ W3s, const float* __restrict__ b3,
    const unsigned short* __restrict__ W4s, const float* __restrict__ b4,
    const unsigned short* __restrict__ x1b, unsigned* __restrict__ encbuf)
{
    __shared__ unsigned short S[128 * A2S];   // 67584 B: A1 (stride A1S) overlaid
    const int tid  = threadIdx.x;
    const int lane = tid & 63;
    const int wave = tid >> 6;
    const int l31  = lane & 31;
    const int h    = lane >> 5;
    const int p0   = blockIdx.x * 8;

    const float b3v0 = b3[(wave * 2 + 0) * 32 + l31];
    const float b3v1 = b3[(wave * 2 + 1) * 32 + l31];

    {
        int r = tid >> 1, q = tid & 1;
        int j = nbr[p0 * KNB + r];
        const uint4* src = (const uint4*)(x1b + j * 128 + q * 64);
        uint4* dst = (uint4*)(S + r * A1S + q * 64);
        #pragma unroll
        for (int i = 0; i < 8; ++i) dst[i] = src[i];
    }
    if (tid < 128) {
        int r = tid;
        int j = nbr[p0 * KNB + r];
        int p = p0 + (r >> 4);
        v8bf z;
        #pragma unroll
        for (int i = 0; i < 8; ++i) z[i] = 0;
        v8bf dv = z;
        dv[0] = (short)f2b(pos[j * 3 + 0] - pos[p * 3 + 0]);
        dv[1] = (short)f2b(pos[j * 3 + 1] - pos[p * 3 + 1]);
        dv[2] = (short)f2b(pos[j * 3 + 2] - pos[p * 3 + 2]);
        *(v8bf*)(S + r * A1S + 128) = dv;
        *(v8bf*)(S + r * A1S + 136) = z;
    }
    __syncthreads();

    const int n1a = (wave * 2 + 0) * 32 + l31;
    const int n1b = (wave * 2 + 1) * 32 + l31;
    unsigned stA[2][16], stB[2][16];
    #pragma unroll
    for (int rtp = 0; rtp < 2; ++rtp) {
        v16f g00 = zero16(), g01 = zero16(), g10 = zero16(), g11 = zero16();
        #pragma unroll
        for (int kc = 0; kc < 9; ++kc) {
            v8bf a0 = *(const v8bf*)(S + (rtp * 64 + l31)      * A1S + kc * 16 + h * 8);
            v8bf a1 = *(const v8bf*)(S + (rtp * 64 + 32 + l31) * A1S + kc * 16 + h * 8);
            int c2 = kc * 2 + h;
            v8bf B0 = *(const v8bf*)(W3s + ((c2 * 256 + n1a) << 3));
            v8bf B1 = *(const v8bf*)(W3s + ((c2 * 256 + n1b) << 3));
            g00 = __builtin_amdgcn_mfma_f32_32x32x16_bf16(a0, B0, g00, 0, 0, 0);
            g10 = __builtin_amdgcn_mfma_f32_32x32x16_bf16(a1, B0, g10, 0, 0, 0);
            g01 = __builtin_amdgcn_mfma_f32_32x32x16_bf16(a0, B1, g01, 0, 0, 0);
            g11 = __builtin_amdgcn_mfma_f32_32x32x16_bf16(a1, B1, g11, 0, 0, 0);
        }
        #pragma unroll
        for (int i = 0; i < 8; ++i) {
            stA[rtp][i]     = pk2(fmaxf(g00[2*i] + b3v0, 0.0f), fmaxf(g00[2*i+1] + b3v0, 0.0f));
            stA[rtp][8 + i] = pk2(fmaxf(g10[2*i] + b3v0, 0.0f), fmaxf(g10[2*i+1] + b3v0, 0.0f));
            stB[rtp][i]     = pk2(fmaxf(g01[2*i] + b3v1, 0.0f), fmaxf(g01[2*i+1] + b3v1, 0.0f));
            stB[rtp][8 + i] = pk2(fmaxf(g11[2*i] + b3v1, 0.0f), fmaxf(g11[2*i+1] + b3v1, 0.0f));
        }
    }
    __syncthreads();

    {
        const int c0 = (wave * 2 + 0) * 32 + l31;
        const int c1 = (wave * 2 + 1) * 32 + l31;
        #pragma unroll
        for (int rtp = 0; rtp < 2; ++rtp) {
            const int rb = rtp * 64;
            #pragma unroll
            for (int i = 0; i < 8; ++i) {
                int row = rb + ((2*i) & 3) + 8 * ((2*i) >> 2) + 4 * h;
                S[row * A2S + c0]        = (unsigned short)(stA[rtp][i] & 0xFFFF);
                S[(row + 1) * A2S + c0]  = (unsigned short)(stA[rtp][i] >> 16);
                S[(row + 32) * A2S + c0] = (unsigned short)(stA[rtp][8 + i] & 0xFFFF);
                S[(row + 33) * A2S + c0] = (unsigned short)(stA[rtp][8 + i] >> 16);
                S[row * A2S + c1]        = (unsigned short)(stB[rtp][i] & 0xFFFF);
                S[(row + 1) * A2S + c1]  = (unsigned short)(stB[rtp][i] >> 16);
                S[(row + 32) * A2S + c1] = (unsigned short)(stB[rtp][8 + i] & 0xFFFF);
                S[(row + 33) * A2S + c1] = (unsigned short)(stB[rtp][8 + i] >> 16);
            }
        }
    }
    __syncthreads();

    const int cloud = batch[p0];
    #pragma unroll
    for (int cp = 0; cp < 2; ++cp) {
        const int ct0 = wave * 4 + cp * 2;
        const int n0 = ct0 * 32 + l31;
        const int n1 = (ct0 + 1) * 32 + l31;
        v8bf B2a[16], B2b[16];
        #pragma unroll
        for (int kc = 0; kc < 16; ++kc) {
            int c2 = kc * 2 + h;
            B2a[kc] = *(const v8bf*)(W4s + ((c2 * 512 + n0) << 3));
            B2b[kc] = *(const v8bf*)(W4s + ((c2 * 512 + n1) << 3));
        }
        float rm0 = -3.4e38f, rm1 = -3.4e38f;
        #pragma unroll
        for (int rtp = 0; rtp < 2; ++rtp) {
            v16f a00 = zero16(), a01 = zero16(), a10 = zero16(), a11 = zero16();
            #pragma unroll
            for (int kc = 0; kc < 16; ++kc) {
                v8bf a0 = *(const v8bf*)(S + (rtp * 64 + l31)      * A2S + kc * 16 + h * 8);
                v8bf a1 = *(const v8bf*)(S + (rtp * 64 + 32 + l31) * A2S + kc * 16 + h * 8);
                a00 = __builtin_amdgcn_mfma_f32_32x32x16_bf16(a0, B2a[kc], a00, 0, 0, 0);
                a10 = __builtin_amdgcn_mfma_f32_32x32x16_bf16(a1, B2a[kc], a10, 0, 0, 0);
                a01 = __builtin_amdgcn_mfma_f32_32x32x16_bf16(a0, B2b[kc], a01, 0, 0, 0);
                a11 = __builtin_amdgcn_mfma_f32_32x32x16_bf16(a1, B2b[kc], a11, 0, 0, 0);
            }
            #pragma unroll
            for (int r = 0; r < 16; ++r) {
                rm0 = fmaxf(rm0, fmaxf(a00[r], a10[r]));
                rm1 = fmaxf(rm1, fmaxf(a01[r], a11[r]));
            }
        }
        rm0 = fmaxf(rm0, __shfl_xor(rm0, 32));
        rm1 = fmaxf(rm1, __shfl_xor(rm1, 32));
        rm0 += b4[ct0 * 32 + l31];
        rm1 += b4[(ct0 + 1) * 32 + l31];
        if (lane < 32) {
            atomicMax(&encbuf[cloud * OUTC + ct0 * 32 + l31], fenc(rm0));
            atomicMax(&encbuf[cloud * OUTC + (ct0 + 1) * 32 + l31], fenc(rm1));
        }
    }
}

// ============================ finalize: decode encoded maxima ================
__global__ void finalize_kernel(const unsigned* __restrict__ encv,
                                float* __restrict__ out)
{
    int i = blockIdx.x * 256 + threadIdx.x;
    if (i < NCLOUD * OUTC) out[i] = fdec(encv[i]);
}

extern "C" void kernel_launch(void* const* d_in, const int* in_sizes, int n_in,
                              void* d_out, int out_size, void* d_ws, size_t ws_size,
                              hipStream_t stream)
{
    const float* pos   = (const float*)d_in[0];
    const int*   nbr   = (const int*)  d_in[1];
    const int*   batch = (const int*)  d_in[2];
    const float* W1    = (const float*)d_in[3];
    const float* b1    = (const float*)d_in[4];
    const float* W2    = (const float*)d_in[5];
    const float* b2    = (const float*)d_in[6];
    const float* W3    = (const float*)d_in[7];
    const float* b3    = (const float*)d_in[8];
    const float* W4    = (const float*)d_in[9];
    const float* b4    = (const float*)d_in[10];

    // new-path workspace: y(16M) | x1b(8M) | W3s(80K) | W4s(256K) | encbuf(32K)
    const size_t NEED = 16777216UL + 8388608UL + 81920UL + 262144UL + 32768UL;

    if (ws_size >= NEED) {
        unsigned short* y   = (unsigned short*)d_ws;
        unsigned short* x1b = (unsigned short*)((char*)d_ws + 16777216);
        unsigned short* W3s = (unsigned short*)((char*)d_ws + 25165824);
        unsigned short* W4s = (unsigned short*)((char*)d_ws + 25247744);
        unsigned*    encbuf = (unsigned*)((char*)d_ws + 25509888);

        sa1_kernel<<<PTOT / 16, 256, 0, stream>>>(pos, nbr, W1, b1, W2, b2, W3, W4,
                                                  W3s, W4s, encbuf, x1b);
        ymap_kernel<<<PTOT / 128, 256, 0, stream>>>(x1b, W3s, b3, y);
        sa2y_kernel<<<PTOT / 8, 256, 0, stream>>>(pos, nbr, batch, W3,
                                                  W4s, b4, y, encbuf);
        finalize_kernel<<<(NCLOUD * OUTC + 255) / 256, 256, 0, stream>>>(encbuf, (float*)d_out);
    } else {
        // fallback: exact R6 pipeline (best previously measured: 248.4 us)
        unsigned short* x1b = (unsigned short*)d_ws;                          // 8 MB
        unsigned short* W3s = (unsigned short*)((char*)d_ws + 8388608);       // 80 KB
        unsigned short* W4s = (unsigned short*)((char*)d_ws + 8470528);       // 256 KB
        unsigned*    encbuf = (unsigned*)((char*)d_ws + 8732672);             // 32 KB

        sa1_kernel<<<PTOT / 16, 256, 0, stream>>>(pos, nbr, W1, b1, W2, b2, W3, W4,
                                                  W3s, W4s, encbuf, x1b);
        sa2_kernel<<<PTOT / 8, 256, 0, stream>>>(pos, nbr, batch, W3s, b3, W4s, b4,
                                                 x1b, encbuf);
        finalize_kernel<<<(NCLOUD * OUTC + 255) / 256, 256, 0, stream>>>(encbuf, (float*)d_out);
    }
}

// Round 10
// 251.340 us; speedup vs baseline: 1.0848x; 1.0848x over previous
//
#include <hip/hip_runtime.h>
#include <hip/hip_bf16.h>

#define PTOT   32768
#define KNB    16
#define NCLOUD 16
#define OUTC   512
#define A1S    168   // sa2 A1 row stride in ushort (336 B, 16B-aligned)
#define A2S    264   // sa2 A2 row stride in ushort (528 B, 16B-aligned)

typedef __attribute__((ext_vector_type(8)))  short v8bf;
typedef __attribute__((ext_vector_type(16))) float v16f;

__device__ __forceinline__ unsigned short f2b(float v) {
    __hip_bfloat16 h = __float2bfloat16(v);
    return *reinterpret_cast<unsigned short*>(&h);
}
__device__ __forceinline__ unsigned pk2(float a, float b) {
    return (unsigned)f2b(a) | ((unsigned)f2b(b) << 16);
}
__device__ __forceinline__ unsigned fenc(float f) {
    unsigned u = __float_as_uint(f);
    return (u & 0x80000000u) ? ~u : (u | 0x80000000u);
}
__device__ __forceinline__ float fdec(unsigned u) {
    unsigned b = (u & 0x80000000u) ? (u & 0x7FFFFFFFu) : ~u;
    return __uint_as_float(b);
}
__device__ __forceinline__ v16f zero16() {
    v16f z;
    #pragma unroll
    for (int i = 0; i < 16; ++i) z[i] = 0.0f;
    return z;
}

// ======= sa1 (MFMA): 16 points/block, single-pass M=256 (R6, unchanged) ====
__global__ __launch_bounds__(256) void sa1_kernel(
    const float* __restrict__ pos, const int* __restrict__ nbr,
    const float* __restrict__ W1, const float* __restrict__ b1,
    const float* __restrict__ W2, const float* __restrict__ b2,
    const float* __restrict__ W3, const float* __restrict__ W4,
    unsigned short* __restrict__ W3s, unsigned short* __restrict__ W4s,
    unsigned* __restrict__ encbuf,
    unsigned short* __restrict__ x1b)
{
    __shared__ unsigned short A1d[256 * 16];   // 8 KB (also prep scratch)
    __shared__ unsigned short A2[256 * 72];    // 36 KB
    const int tid  = threadIdx.x;
    const int lane = tid & 63;
    const int wave = tid >> 6;
    const int l31  = lane & 31;
    const int h    = lane >> 5;

    // ---- absorbed prep, coalesced via LDS transpose (blocks 0..49)
    {
        const int b = blockIdx.x;
        if (b < 32) {                          // W4s tile c2 = b: 8 rows x 512 cols
            #pragma unroll
            for (int it = 0; it < 16; ++it) {
                int e = tid + it * 256;        // 0..4095
                int jj = e >> 9, n = e & 511;
                A1d[e] = f2b(W4[(b * 8 + jj) * 512 + n]);   // coalesced read
            }
            __syncthreads();
            #pragma unroll
            for (int it = 0; it < 16; ++it) {
                int o = tid + it * 256;        // W4s idx = b*4096 + n*8 + j
                W4s[b * 4096 + o] = A1d[(o & 7) * 512 + (o >> 3)];  // coalesced write
            }
            __syncthreads();                   // A1d reusable below
        } else if (b < 50) {                   // W3s tile c2 = b-32: 8 rows x 256 cols
            int c2 = b - 32;
            #pragma unroll
            for (int it = 0; it < 8; ++it) {
                int e = tid + it * 256;        // 0..2047
                int jj = e >> 8, n = e & 255;
                int k = c2 * 8 + jj;
                A1d[e] = f2b(k < 131 ? W3[k * 256 + n] : 0.0f);
            }
            __syncthreads();
            #pragma unroll
            for (int it = 0; it < 8; ++it) {
                int o = tid + it * 256;        // W3s idx = c2*2048 + n*8 + j
                W3s[c2 * 2048 + o] = A1d[(o & 7) * 256 + (o >> 3)];
            }
            __syncthreads();
        }
        if (b == 2047) {                       // encbuf init (fenc-domain -inf)
            for (int i = tid; i < NCLOUD * OUTC; i += 256) encbuf[i] = 0u;
        }
    }

    // ---- weight fragments from global fp32 (block-invariant)
    const int c1 = (wave >> 1) * 32 + l31;       // G1 col (col-tile = wave>>1)
    v8bf b1f;
    #pragma unroll
    for (int i = 0; i < 8; ++i) b1f[i] = 0;
    if (h == 0) {   // k=0..2 real, rest zero
        b1f[0] = (short)f2b(W1[c1]);
        b1f[1] = (short)f2b(W1[64 + c1]);
        b1f[2] = (short)f2b(W1[128 + c1]);
    }
    const float b1v = b1[c1];
    const int cW2 = wave * 32 + l31;             // G2 col (col-tile = wave)
    v8bf B2[4];
    #pragma unroll
    for (int kc = 0; kc < 4; ++kc)
        #pragma unroll
        for (int j = 0; j < 8; ++j)
            B2[kc][j] = (short)f2b(W2[(kc * 16 + h * 8 + j) * 128 + cW2]);
    const float b2v = b2[cW2];

    const int p0 = blockIdx.x * 16;

    // ---- stage A1d: 256 rows = (point, nbr), one thread per row
    {
        int r = tid;
        int j = nbr[p0 * KNB + r];
        int p = p0 + (r >> 4);
        v8bf z;
        #pragma unroll
        for (int i = 0; i < 8; ++i) z[i] = 0;
        v8bf dv = z;
        dv[0] = (short)f2b(pos[j * 3 + 0] - pos[p * 3 + 0]);
        dv[1] = (short)f2b(pos[j * 3 + 1] - pos[p * 3 + 1]);
        dv[2] = (short)f2b(pos[j * 3 + 2] - pos[p * 3 + 2]);
        *(v8bf*)(A1d + r * 16)     = dv;
        *(v8bf*)(A1d + r * 16 + 8) = z;
    }
    __syncthreads();

    // ---- G1: wave covers col-tile (wave>>1), row-tiles {(wave&1)+2*rr}
    #pragma unroll
    for (int rr = 0; rr < 4; ++rr) {
        const int rt = (wave & 1) + rr * 2;
        v8bf a = *(const v8bf*)(A1d + (rt * 32 + l31) * 16 + h * 8);
        v16f acc = __builtin_amdgcn_mfma_f32_32x32x16_bf16(a, b1f, zero16(), 0, 0, 0);
        #pragma unroll
        for (int r = 0; r < 16; ++r) {
            int row = rt * 32 + (r & 3) + 8 * (r >> 2) + 4 * h;
            A2[row * 72 + c1] = f2b(fmaxf(acc[r] + b1v, 0.0f));
        }
    }
    __syncthreads();

    // ---- G2: wave's col-tile over 8 row-tiles; per-rt max -> 2 points each
    #pragma unroll
    for (int rt = 0; rt < 8; ++rt) {
        v16f acc = zero16();
        #pragma unroll
        for (int kc = 0; kc < 4; ++kc) {
            v8bf a = *(const v8bf*)(A2 + (rt * 32 + l31) * 72 + kc * 16 + h * 8);
            acc = __builtin_amdgcn_mfma_f32_32x32x16_bf16(a, B2[kc], acc, 0, 0, 0);
        }
        float ma = acc[0], mb = acc[8];
        #pragma unroll
        for (int r = 1; r < 8; ++r) { ma = fmaxf(ma, acc[r]); mb = fmaxf(mb, acc[8 + r]); }
        ma = fmaxf(ma, __shfl_xor(ma, 32));
        mb = fmaxf(mb, __shfl_xor(mb, 32));
        int p = p0 + rt * 2 + h;
        float m = h ? mb : ma;
        x1b[p * 128 + cW2] = f2b(m + b2v);
    }
}

// ==== sa2 (MFMA): R0-proven body + T1 XCD-chunked block swizzle =============
// R9 lesson: algebraic dedup (y-map) doubles gather bytes and loses 21us;
// the R0 body stands. Only change here: bijective XCD-chunked remap
// bid = (blockIdx.x%8)*512 + blockIdx.x/8  (4096%8==0). HW round-robins
// wg->XCD by blockIdx%8, so each XCD now covers 512 CONTIGUOUS work-blocks
// = 2 clouds = a 1MB x1b gather working set that fits its 4MB L2 (was: every
// XCD streaming all 16 clouds' 8MB). Cuts A1-stage gather latency (L2-hit
// instead of HBM) and localizes per-cloud encbuf atomics to one XCD.
__global__ __launch_bounds__(256) void sa2_kernel(
    const float* __restrict__ pos, const int* __restrict__ nbr,
    const int* __restrict__ batch,
    const unsigned short* __restrict__ W3s, const float* __restrict__ b3,
    const unsigned short* __restrict__ W4s, const float* __restrict__ b4,
    const unsigned short* __restrict__ x1b, unsigned* __restrict__ encbuf)
{
    __shared__ unsigned short S[128 * A2S];   // 67584 B: A1 (stride A1S) overlaid
    const int tid  = threadIdx.x;
    const int lane = tid & 63;
    const int wave = tid >> 6;
    const int l31  = lane & 31;
    const int h    = lane >> 5;
    const int bid  = (blockIdx.x & 7) * 512 + (blockIdx.x >> 3);   // XCD-chunked
    const int p0   = bid * 8;

    const float b3v0 = b3[(wave * 2 + 0) * 32 + l31];
    const float b3v1 = b3[(wave * 2 + 1) * 32 + l31];

    // ---- stage A1: 128 rows = (point, nbr); 2 threads/row, 128 B each
    {
        int r = tid >> 1, q = tid & 1;
        int j = nbr[p0 * KNB + r];
        const uint4* src = (const uint4*)(x1b + j * 128 + q * 64);
        uint4* dst = (uint4*)(S + r * A1S + q * 64);
        #pragma unroll
        for (int i = 0; i < 8; ++i) dst[i] = src[i];
    }
    if (tid < 128) {
        int r = tid;
        int j = nbr[p0 * KNB + r];
        int p = p0 + (r >> 4);
        v8bf z;
        #pragma unroll
        for (int i = 0; i < 8; ++i) z[i] = 0;
        v8bf dv = z;
        dv[0] = (short)f2b(pos[j * 3 + 0] - pos[p * 3 + 0]);
        dv[1] = (short)f2b(pos[j * 3 + 1] - pos[p * 3 + 1]);
        dv[2] = (short)f2b(pos[j * 3 + 2] - pos[p * 3 + 2]);
        *(v8bf*)(S + r * A1S + 128) = dv;
        *(v8bf*)(S + r * A1S + 136) = z;
    }
    __syncthreads();

    // ---- GEMM1: kc-streamed B, looped over 2 row-tile-pairs; kc=9 pad skipped
    const int n1a = (wave * 2 + 0) * 32 + l31;
    const int n1b = (wave * 2 + 1) * 32 + l31;
    unsigned stA[2][16], stB[2][16];   // [rtp][..] ci=0 / ci=1
    #pragma unroll
    for (int rtp = 0; rtp < 2; ++rtp) {
        v16f g00 = zero16(), g01 = zero16(), g10 = zero16(), g11 = zero16();
        #pragma unroll
        for (int kc = 0; kc < 9; ++kc) {
            v8bf a0 = *(const v8bf*)(S + (rtp * 64 + l31)      * A1S + kc * 16 + h * 8);
            v8bf a1 = *(const v8bf*)(S + (rtp * 64 + 32 + l31) * A1S + kc * 16 + h * 8);
            int c2 = kc * 2 + h;
            v8bf B0 = *(const v8bf*)(W3s + ((c2 * 256 + n1a) << 3));
            v8bf B1 = *(const v8bf*)(W3s + ((c2 * 256 + n1b) << 3));
            g00 = __builtin_amdgcn_mfma_f32_32x32x16_bf16(a0, B0, g00, 0, 0, 0);
            g10 = __builtin_amdgcn_mfma_f32_32x32x16_bf16(a1, B0, g10, 0, 0, 0);
            g01 = __builtin_amdgcn_mfma_f32_32x32x16_bf16(a0, B1, g01, 0, 0, 0);
            g11 = __builtin_amdgcn_mfma_f32_32x32x16_bf16(a1, B1, g11, 0, 0, 0);
        }
        #pragma unroll
        for (int i = 0; i < 8; ++i) {
            stA[rtp][i]     = pk2(fmaxf(g00[2*i] + b3v0, 0.0f), fmaxf(g00[2*i+1] + b3v0, 0.0f));
            stA[rtp][8 + i] = pk2(fmaxf(g10[2*i] + b3v0, 0.0f), fmaxf(g10[2*i+1] + b3v0, 0.0f));
            stB[rtp][i]     = pk2(fmaxf(g01[2*i] + b3v1, 0.0f), fmaxf(g01[2*i+1] + b3v1, 0.0f));
            stB[rtp][8 + i] = pk2(fmaxf(g11[2*i] + b3v1, 0.0f), fmaxf(g11[2*i+1] + b3v1, 0.0f));
        }
    }
    __syncthreads();   // all A1 reads complete — safe to overwrite with A2

    // ---- store A2 = bf16(relu(GEMM1)) row-major, stride A2S
    {
        const int c0 = (wave * 2 + 0) * 32 + l31;
        const int c1 = (wave * 2 + 1) * 32 + l31;
        #pragma unroll
        for (int rtp = 0; rtp < 2; ++rtp) {
            const int rb = rtp * 64;
            #pragma unroll
            for (int i = 0; i < 8; ++i) {
                int row = rb + ((2*i) & 3) + 8 * ((2*i) >> 2) + 4 * h;
                S[row * A2S + c0]        = (unsigned short)(stA[rtp][i] & 0xFFFF);
                S[(row + 1) * A2S + c0]  = (unsigned short)(stA[rtp][i] >> 16);
                S[(row + 32) * A2S + c0] = (unsigned short)(stA[rtp][8 + i] & 0xFFFF);
                S[(row + 33) * A2S + c0] = (unsigned short)(stA[rtp][8 + i] >> 16);
                S[row * A2S + c1]        = (unsigned short)(stB[rtp][i] & 0xFFFF);
                S[(row + 1) * A2S + c1]  = (unsigned short)(stB[rtp][i] >> 16);
                S[(row + 32) * A2S + c1] = (unsigned short)(stB[rtp][8 + i] & 0xFFFF);
                S[(row + 33) * A2S + c1] = (unsigned short)(stB[rtp][8 + i] >> 16);
            }
        }
    }
    __syncthreads();   // A2 ready

    // ---- GEMM2: ct-pair outer (B held, reused by both row-tile-pairs)
    const int cloud = batch[p0];
    #pragma unroll
    for (int cp = 0; cp < 2; ++cp) {
        const int ct0 = wave * 4 + cp * 2;
        const int n0 = ct0 * 32 + l31;
        const int n1 = (ct0 + 1) * 32 + l31;
        v8bf B2a[16], B2b[16];
        #pragma unroll
        for (int kc = 0; kc < 16; ++kc) {
            int c2 = kc * 2 + h;
            B2a[kc] = *(const v8bf*)(W4s + ((c2 * 512 + n0) << 3));
            B2b[kc] = *(const v8bf*)(W4s + ((c2 * 512 + n1) << 3));
        }
        float rm0 = -3.4e38f, rm1 = -3.4e38f;
        #pragma unroll
        for (int rtp = 0; rtp < 2; ++rtp) {
            v16f a00 = zero16(), a01 = zero16(), a10 = zero16(), a11 = zero16();
            #pragma unroll
            for (int kc = 0; kc < 16; ++kc) {
                v8bf a0 = *(const v8bf*)(S + (rtp * 64 + l31)      * A2S + kc * 16 + h * 8);
                v8bf a1 = *(const v8bf*)(S + (rtp * 64 + 32 + l31) * A2S + kc * 16 + h * 8);
                a00 = __builtin_amdgcn_mfma_f32_32x32x16_bf16(a0, B2a[kc], a00, 0, 0, 0);
                a10 = __builtin_amdgcn_mfma_f32_32x32x16_bf16(a1, B2a[kc], a10, 0, 0, 0);
                a01 = __builtin_amdgcn_mfma_f32_32x32x16_bf16(a0, B2b[kc], a01, 0, 0, 0);
                a11 = __builtin_amdgcn_mfma_f32_32x32x16_bf16(a1, B2b[kc], a11, 0, 0, 0);
            }
            #pragma unroll
            for (int r = 0; r < 16; ++r) {
                rm0 = fmaxf(rm0, fmaxf(a00[r], a10[r]));
                rm1 = fmaxf(rm1, fmaxf(a01[r], a11[r]));
            }
        }
        rm0 = fmaxf(rm0, __shfl_xor(rm0, 32));
        rm1 = fmaxf(rm1, __shfl_xor(rm1, 32));
        rm0 += b4[ct0 * 32 + l31];
        rm1 += b4[(ct0 + 1) * 32 + l31];
        if (lane < 32) {
            atomicMax(&encbuf[cloud * OUTC + ct0 * 32 + l31], fenc(rm0));
            atomicMax(&encbuf[cloud * OUTC + (ct0 + 1) * 32 + l31], fenc(rm1));
        }
    }
}

// ============================ finalize: decode encoded maxima ================
__global__ void finalize_kernel(const unsigned* __restrict__ encv,
                                float* __restrict__ out)
{
    int i = blockIdx.x * 256 + threadIdx.x;
    if (i < NCLOUD * OUTC) out[i] = fdec(encv[i]);
}

extern "C" void kernel_launch(void* const* d_in, const int* in_sizes, int n_in,
                              void* d_out, int out_size, void* d_ws, size_t ws_size,
                              hipStream_t stream)
{
    const float* pos   = (const float*)d_in[0];
    const int*   nbr   = (const int*)  d_in[1];
    const int*   batch = (const int*)  d_in[2];
    const float* W1    = (const float*)d_in[3];
    const float* b1    = (const float*)d_in[4];
    const float* W2    = (const float*)d_in[5];
    const float* b2    = (const float*)d_in[6];
    const float* W3    = (const float*)d_in[7];
    const float* b3    = (const float*)d_in[8];
    const float* W4    = (const float*)d_in[9];
    const float* b4    = (const float*)d_in[10];

    unsigned short* x1b = (unsigned short*)d_ws;                          // 8 MB
    unsigned short* W3s = (unsigned short*)((char*)d_ws + 8388608);       // 80 KB
    unsigned short* W4s = (unsigned short*)((char*)d_ws + 8470528);       // 256 KB
    unsigned*    encbuf = (unsigned*)((char*)d_ws + 8732672);             // 32 KB

    sa1_kernel<<<PTOT / 16, 256, 0, stream>>>(pos, nbr, W1, b1, W2, b2, W3, W4,
                                              W3s, W4s, encbuf, x1b);
    sa2_kernel<<<PTOT / 8, 256, 0, stream>>>(pos, nbr, batch, W3s, b3, W4s, b4,
                                             x1b, encbuf);
    finalize_kernel<<<(NCLOUD * OUTC + 255) / 256, 256, 0, stream>>>(encbuf, (float*)d_out);
}